// Round 1
// baseline (273.337 us; speedup 1.0000x reference)
//
#include <hip/hip_runtime.h>
#include <stdint.h>

#define BB 4
#define CC 256
#define NN 4096   // H*W = 64*64
#define RR 32

typedef __attribute__((ext_vector_type(8)))  short  short8;   // 8 bf16 = 4 VGPR (MFMA A/B frag)
typedef __attribute__((ext_vector_type(4)))  short  short4v;  // 4 bf16 = 8B
typedef __attribute__((ext_vector_type(16))) float  floatx16; // MFMA C/D frag

// RNE-ish float->bf16 (round half up; inputs are normal finite values)
static __device__ __forceinline__ unsigned short f2bf(float f) {
    union { float f; unsigned int u; } v; v.f = f;
    unsigned int u = v.u;
    u += 0x7fffu + ((u >> 16) & 1u);
    return (unsigned short)(u >> 16);
}

static __device__ __forceinline__ float exp2_fast(float x) {
#if __has_builtin(__builtin_amdgcn_exp2f)
    return __builtin_amdgcn_exp2f(x);
#else
    return exp2f(x);
#endif
}

// ---------------- K1: depthwise 3x3, one dilation, +bias ----------------
// one thread per (b,c,n); D[b][c][n] fp32
__global__ void k_depthwise(const float* __restrict__ x, const float* __restrict__ w,
                            const float* __restrict__ bias, float* __restrict__ D, int dil) {
    int idx = blockIdx.x * 256 + threadIdx.x;     // b*C*N + c*N + n
    int n  = idx & (NN - 1);
    int bc = idx >> 12;                            // b*C + c
    int c  = bc & (CC - 1);
    int h = n >> 6, wq = n & 63;
    const float* xp = x + (size_t)bc * NN;
    float acc = bias[c];
    #pragma unroll
    for (int ky = 0; ky < 3; ky++) {
        int hh = h + dil * (ky - 1);
        #pragma unroll
        for (int kx = 0; kx < 3; kx++) {
            int ww = wq + dil * (kx - 1);
            float xv = ((unsigned)hh < 64u && (unsigned)ww < 64u) ? xp[hh * 64 + ww] : 0.f;
            acc += xv * w[c * 9 + ky * 3 + kx];
        }
    }
    D[idx] = acc;
}

// ---------------- K2: pointwise 1x1 C->R, +bias, emit bf16 Q/K/V --------
// block: 256 thr = 64 n x 4 r-groups. mode 0: V[b][r][n]; 1: Qt[b][n][r]*log2e; 2: Kt[b][n][r]
__global__ void k_pointwise(const float* __restrict__ D, const float* __restrict__ pw,
                            const float* __restrict__ pb, unsigned short* __restrict__ outp,
                            int mode) {
    int b  = blockIdx.y;
    int n  = blockIdx.x * 64 + (threadIdx.x & 63);
    int rg = threadIdx.x >> 6;                     // 0..3 -> r = rg*8..rg*8+7
    float acc[8];
    #pragma unroll
    for (int j = 0; j < 8; j++) acc[j] = pb[rg * 8 + j];
    const float* Dp = D + (size_t)b * CC * NN + n;
    #pragma unroll 4
    for (int c = 0; c < CC; c++) {
        float d = Dp[(size_t)c * NN];
        #pragma unroll
        for (int j = 0; j < 8; j++) acc[j] += d * pw[(rg * 8 + j) * CC + c];
    }
    if (mode == 0) {
        #pragma unroll
        for (int j = 0; j < 8; j++)
            outp[((size_t)b * RR + rg * 8 + j) * NN + n] = f2bf(acc[j]);
    } else {
        const float s = (mode == 1) ? 1.4426950408889634f : 1.0f;  // fold log2(e) into Q
        short8 v;
        #pragma unroll
        for (int j = 0; j < 8; j++) v[j] = (short)f2bf(acc[j] * s);
        *(short8*)(outp + ((size_t)b * NN + n) * RR + rg * 8) = v;
    }
}

// ---------------- K3: fused attention (no-max online softmax), partials --
// grid (32 itile-groups, 4 j-chunks, 4 b), block 256 = 4 independent waves.
// Wave: 32-i tile, loops 32 j-steps of 32 j. S^T via mfma_32x32x16_bf16; its
// C-frag regs 0..7 / 8..15 ARE the PV A-frags; V B-frag loads permuted to match.
__global__ __launch_bounds__(256, 2) void k_attn(
    const unsigned short* __restrict__ Qt, const unsigned short* __restrict__ Kt,
    const unsigned short* __restrict__ V, float* __restrict__ OP, float* __restrict__ LP)
{
    int wave = threadIdx.x >> 6;
    int lane = threadIdx.x & 63;
    int l31  = lane & 31;
    int h    = lane >> 5;
    int itile = blockIdx.x * 4 + wave;             // 0..127
    int chunk = blockIdx.y;                        // 0..3 -> j in [chunk*1024, +1024)
    int b     = blockIdx.z;
    int i     = itile * 32 + l31;

    // Q (B-operand of S^T mfma): B[k=c][n=i], lane n=l31, k=8h+jj
    const short8* qrow = (const short8*)(Qt + ((size_t)b * NN + i) * RR);
    short8 q1 = qrow[h], q2 = qrow[2 + h];

    floatx16 acc = {};
    float lacc = 0.f;
    const unsigned short* Kb = Kt + (size_t)b * NN * RR;
    const unsigned short* Vb = V  + (size_t)b * RR * NN;

    for (int js = 0; js < 32; js++) {
        int jb = chunk * 1024 + js * 32;
        // K^T rows (A-operand): A[m=j][k=c], lane m=l31 -> row j=jb+l31
        const short8* krow = (const short8*)(Kb + (size_t)(jb + l31) * RR);
        short8 ka1 = krow[h], ka2 = krow[2 + h];
        floatx16 st = {};
        st = __builtin_amdgcn_mfma_f32_32x32x16_bf16(ka1, q1, st, 0, 0, 0);
        st = __builtin_amdgcn_mfma_f32_32x32x16_bf16(ka2, q2, st, 0, 0, 0);
        // P = exp(S) (Q pre-scaled by log2e); row sums for this lane's i=l31
        float p[16];
        #pragma unroll
        for (int r = 0; r < 16; r++) { p[r] = exp2_fast(st[r]); lacc += p[r]; }
        short8 pa1, pa2;
        #pragma unroll
        for (int r = 0; r < 8; r++) {
            pa1[r] = (short)f2bf(p[r]);
            pa2[r] = (short)f2bf(p[r + 8]);
        }
        // V B-frags, k-order matches C-frag reg order: lane (n=c=l31, half h)
        // slots 0..3 -> j = jb + 4h + 0..3 ; slots 4..7 -> j = jb + 4h + 8..11
        const short4v* vp = (const short4v*)(Vb + (size_t)l31 * NN + jb + 4 * h);
        short8 vb1, vb2;
        #pragma unroll
        for (int t = 0; t < 4; t++) {
            vb1[t] = vp[0][t]; vb1[t + 4] = vp[2][t];   // j-set {0..15} permuted
            vb2[t] = vp[4][t]; vb2[t + 4] = vp[6][t];   // j-set {16..31} permuted
        }
        acc = __builtin_amdgcn_mfma_f32_32x32x16_bf16(pa1, vb1, acc, 0, 0, 0);
        acc = __builtin_amdgcn_mfma_f32_32x32x16_bf16(pa2, vb2, acc, 0, 0, 0);
    }
    // store partials in native frag layout (fully coalesced)
    size_t slot = ((size_t)(b * 128 + itile) * 4 + chunk) * 64 + lane;
    float* op = OP + slot * 16;
    #pragma unroll
    for (int r = 0; r < 16; r++) op[r] = acc[r];
    LP[slot] = lacc;
}

// ---------------- K4: merge chunk partials -> Fpmap[b][c][i] fp32 -------
__global__ void k_merge(const float* __restrict__ OP, const float* __restrict__ LP,
                        float* __restrict__ FM) {
    int itile = blockIdx.x, b = blockIdx.y;
    int lane = threadIdx.x, l31 = lane & 31, h = lane >> 5;
    __shared__ float linv[32];
    size_t base = (size_t)(b * 128 + itile) * 4;
    float ls = 0.f;
    #pragma unroll
    for (int ch = 0; ch < 4; ch++) ls += LP[(base + ch) * 64 + lane];
    ls += __shfl_xor(ls, 32, 64);                  // combine the two j-halves
    if (lane < 32) linv[lane] = 1.f / ls;          // index = i_local = l31
    __syncthreads();
    float o[16];
    #pragma unroll
    for (int r = 0; r < 16; r++) o[r] = 0.f;
    for (int ch = 0; ch < 4; ch++) {
        const float* op = OP + ((base + ch) * 64 + lane) * 16;
        #pragma unroll
        for (int r = 0; r < 16; r++) o[r] += op[r];
    }
    int ibase = itile * 32;
    float* fm = FM + (size_t)b * RR * NN;
    #pragma unroll
    for (int r = 0; r < 16; r++) {
        int il = (r & 3) + 8 * (r >> 2) + 4 * h;   // C/D row mapping (m74/m101)
        fm[(size_t)l31 * NN + ibase + il] = o[r] * linv[il];
    }
}

// ---------------- K5: 1x1 conv R->C + bias + residual -------------------
__global__ void k_convout(const float* __restrict__ x, const float* __restrict__ FM,
                          const float* __restrict__ cw, const float* __restrict__ cb,
                          float* __restrict__ out) {
    int co = blockIdx.y, b = blockIdx.z;
    int n4 = blockIdx.x * 256 + threadIdx.x;       // float4 index, N/4 = 1024
    const float4* fmp = (const float4*)(FM + (size_t)b * RR * NN);
    float ax = 0.f, ay = 0.f, az = 0.f, aw = 0.f;
    #pragma unroll 8
    for (int r = 0; r < RR; r++) {
        float wv = cw[co * RR + r];
        float4 v = fmp[r * (NN / 4) + n4];
        ax += wv * v.x; ay += wv * v.y; az += wv * v.z; aw += wv * v.w;
    }
    size_t o = (size_t)(b * CC + co) * (NN / 4) + n4;
    float4 xv = ((const float4*)x)[o];
    float bias = cb[co];
    float4 res;
    res.x = xv.x + ax + bias; res.y = xv.y + ay + bias;
    res.z = xv.z + az + bias; res.w = xv.w + aw + bias;
    ((float4*)out)[o] = res;
}

extern "C" void kernel_launch(void* const* d_in, const int* in_sizes, int n_in,
                              void* d_out, int out_size, void* d_ws, size_t ws_size,
                              hipStream_t stream) {
    const float* x = (const float*)d_in[0];
    char* ws = (char*)d_ws;
    // workspace layout (~29.5 MB total)
    float*          D  = (float*)(ws);                        // 16 MB, reused per dilation
    unsigned short* Qt = (unsigned short*)(ws + 16777216);    // 1 MB  (b,n,r) bf16 *log2e
    unsigned short* Kt = (unsigned short*)(ws + 17825792);    // 1 MB  (b,n,r) bf16
    unsigned short* V  = (unsigned short*)(ws + 18874368);    // 1 MB  (b,r,n) bf16
    float*          OP = (float*)(ws + 19922944);             // 8 MB  attention O partials
    float*          LP = (float*)(ws + 28311552);             // 0.5 MB softmax-denom partials
    float*          FM = (float*)(ws + 28835840);             // 2 MB  Fpmap (b,r,n) fp32

    const int dils[3] = {1, 3, 5};
    for (int k = 0; k < 3; k++) {
        const float* dw_w = (const float*)d_in[1 + k * 4];
        const float* dw_b = (const float*)d_in[2 + k * 4];
        const float* pw_w = (const float*)d_in[3 + k * 4];
        const float* pw_b = (const float*)d_in[4 + k * 4];
        hipLaunchKernelGGL(k_depthwise, dim3(BB * CC * NN / 256), dim3(256), 0, stream,
                           x, dw_w, dw_b, D, dils[k]);
        unsigned short* dst = (k == 0) ? V : (k == 1 ? Qt : Kt);  // Fp1=V, Fp2=Q, Fp3=K
        hipLaunchKernelGGL(k_pointwise, dim3(64, BB), dim3(256), 0, stream,
                           D, pw_w, pw_b, dst, k);
    }
    hipLaunchKernelGGL(k_attn, dim3(32, 4, BB), dim3(256), 0, stream, Qt, Kt, V, OP, LP);
    hipLaunchKernelGGL(k_merge, dim3(128, BB), dim3(64), 0, stream, OP, LP, FM);
    hipLaunchKernelGGL(k_convout, dim3(4, CC, BB), dim3(256), 0, stream,
                       x, FM, (const float*)d_in[13], (const float*)d_in[14], (float*)d_out);
}

// Round 3
// 200.917 us; speedup vs baseline: 1.3604x; 1.3604x over previous
//
#include <hip/hip_runtime.h>
#include <stdint.h>

#define BB 4
#define CC 256
#define NN 4096   // H*W = 64*64
#define RR 32
#define NCHUNK 8
#define JSTEPS (NN / NCHUNK / 32)   // 16
#define CSIZE  (NN / NCHUNK)        // 512

typedef __attribute__((ext_vector_type(8)))  short  short8;   // 8 bf16 (MFMA A/B frag)
typedef __attribute__((ext_vector_type(4)))  short  short4v;  // 4 bf16 = 8B
typedef __attribute__((ext_vector_type(16))) float  floatx16; // MFMA C/D frag

static __device__ __forceinline__ unsigned short f2bf(float f) {
    union { float f; unsigned int u; } v; v.f = f;
    unsigned int u = v.u;
    u += 0x7fffu + ((u >> 16) & 1u);
    return (unsigned short)(u >> 16);
}

static __device__ __forceinline__ float exp2_fast(float x) {
#if __has_builtin(__builtin_amdgcn_exp2f)
    return __builtin_amdgcn_exp2f(x);
#else
    return exp2f(x);
#endif
}

// ---------------- K1: fused 3x dsconv (depthwise+pointwise) -> Q,K,V bf16 ----
// grid (64 h-rows, B), block 512 = 8 waves. Wave = one row (lane = w), c-split
// 32 c per wave; depthwise taps via __shfl (+/- d), pointwise folded in-loop.
// Cross-wave reduce through 64KB LDS. Phases: c1->V, c2->Q(*log2e), c3->K.
__global__ __launch_bounds__(512, 2) void k_qkv(
    const float* __restrict__ x,
    const float* __restrict__ w1, const float* __restrict__ b1,
    const float* __restrict__ p1, const float* __restrict__ pb1,
    const float* __restrict__ w2, const float* __restrict__ b2,
    const float* __restrict__ p2, const float* __restrict__ pb2,
    const float* __restrict__ w3, const float* __restrict__ b3,
    const float* __restrict__ p3, const float* __restrict__ pb3,
    unsigned short* __restrict__ V, unsigned short* __restrict__ Qt,
    unsigned short* __restrict__ Kt)
{
    __shared__ float part[8][32][64];   // 64 KB
    const float* DWW[3] = {w1, w2, w3};
    const float* DWB[3] = {b1, b2, b3};
    const float* PWW[3] = {p1, p2, p3};
    const float* PWB[3] = {pb1, pb2, pb3};
    unsigned short* OUTP[3] = {V, Qt, Kt};
    const int DILS[3] = {1, 3, 5};

    int t = threadIdx.x;
    int lane = t & 63;
    int wv = __builtin_amdgcn_readfirstlane(t >> 6);   // 0..7, wave-uniform SGPR
    int rg = t >> 6;                                    // reduce-phase r-group
    int h = blockIdx.x, b = blockIdx.y;
    int n = h * 64 + lane;

    #pragma unroll
    for (int p = 0; p < 3; p++) {
        const int d = DILS[p];
        const float* dww = DWW[p];
        const float* dwb = DWB[p];
        const float* pww = PWW[p];
        float acc[32];
        #pragma unroll
        for (int r = 0; r < 32; r++) acc[r] = 0.f;
        int hm = h - d, hp = h + d;
        int hmc = hm < 0 ? 0 : hm, hpc = hp > 63 ? 63 : hp;
        bool okm = hm >= 0, okp = hp <= 63;
        bool okl = lane >= d, okr = lane < 64 - d;
        int lml = lane >= d ? lane - d : 0;            // clamped shuffle sources
        int lpr = lane + d <= 63 ? lane + d : 63;
        #pragma unroll 2
        for (int ci = 0; ci < 32; ci++) {
            int c = wv * 32 + ci;
            const float* xc = x + (size_t)(b * CC + c) * NN;
            float rm = xc[hmc * 64 + lane]; rm = okm ? rm : 0.f;
            float r0 = xc[h * 64 + lane];
            float rp = xc[hpc * 64 + lane]; rp = okp ? rp : 0.f;
            const float* wc = dww + c * 9;
            float dcv = dwb[c];
            {
                float lv = __shfl(rm, lml, 64); lv = okl ? lv : 0.f;
                float rv = __shfl(rm, lpr, 64); rv = okr ? rv : 0.f;
                dcv += lv * wc[0] + rm * wc[1] + rv * wc[2];
            }
            {
                float lv = __shfl(r0, lml, 64); lv = okl ? lv : 0.f;
                float rv = __shfl(r0, lpr, 64); rv = okr ? rv : 0.f;
                dcv += lv * wc[3] + r0 * wc[4] + rv * wc[5];
            }
            {
                float lv = __shfl(rp, lml, 64); lv = okl ? lv : 0.f;
                float rv = __shfl(rp, lpr, 64); rv = okr ? rv : 0.f;
                dcv += lv * wc[6] + rp * wc[7] + rv * wc[8];
            }
            const float* pwc = pww + c;   // column c of pw[r][c], r-stride CC
            #pragma unroll
            for (int r = 0; r < 32; r++) acc[r] += dcv * pwc[r * CC];
        }
        #pragma unroll
        for (int r = 0; r < 32; r++) part[wv][r][lane] = acc[r];
        __syncthreads();
        // reduce 8 wave-partials; thread (n=lane, rg) owns r = rg*4..rg*4+3
        const float* pwb = PWB[p];
        if (p == 0) {
            #pragma unroll
            for (int j = 0; j < 4; j++) {
                int r = rg * 4 + j;
                float s = pwb[r];
                #pragma unroll
                for (int w2 = 0; w2 < 8; w2++) s += part[w2][r][lane];
                OUTP[0][((size_t)(b * RR + r)) * NN + n] = f2bf(s);   // V[b][r][n]
            }
        } else {
            const float sc = (p == 1) ? 1.4426950408889634f : 1.f;    // Q *= log2e
            short4v vv;
            #pragma unroll
            for (int j = 0; j < 4; j++) {
                int r = rg * 4 + j;
                float s = pwb[r];
                #pragma unroll
                for (int w2 = 0; w2 < 8; w2++) s += part[w2][r][lane];
                vv[j] = (short)f2bf(s * sc);
            }
            *(short4v*)(OUTP[p] + ((size_t)b * NN + n) * RR + rg * 4) = vv; // [b][n][r]
        }
        __syncthreads();   // part reused next phase
    }
}

// ---------------- K2: fused attention, LDS-staged V, 8 chunks ----------------
// grid (32, NCHUNK, B), block 256 = 4 waves (4 itiles, same chunk -> shared V).
__global__ __launch_bounds__(256, 4) void k_attn(
    const unsigned short* __restrict__ Qt, const unsigned short* __restrict__ Kt,
    const unsigned short* __restrict__ V, float* __restrict__ OP, float* __restrict__ LP)
{
    __shared__ unsigned short Vt[32][36];   // padded rows: 72B, conflict-free frags
    int t = threadIdx.x;
    int wave = t >> 6, lane = t & 63, l31 = lane & 31, h = lane >> 5;
    int itile = blockIdx.x * 4 + wave;
    int chunk = blockIdx.y;
    int b = blockIdx.z;
    int i = itile * 32 + l31;

    const short8* qrow = (const short8*)(Qt + ((size_t)b * NN + i) * RR);
    short8 q1 = qrow[h], q2 = qrow[2 + h];

    const unsigned short* Kb = Kt + (size_t)b * NN * RR;
    const unsigned short* Vb = V + (size_t)b * RR * NN;

    // staging map: thread t -> V row sr (of 32), 8B chunk sc (of 8)
    int sr = t >> 3, sc = t & 7;
    const unsigned short* vsrc = Vb + (size_t)sr * NN + chunk * CSIZE + sc * 4;

    floatx16 acc = {};
    float lacc = 0.f;

    short4v vreg = *(const short4v*)vsrc;   // prefetch V tile for step 0
    // prefetch K frags for step 0
    const short8* krow0 = (const short8*)(Kb + (size_t)(chunk * CSIZE + l31) * RR);
    short8 ka1 = krow0[h], ka2 = krow0[2 + h];

    for (int js = 0; js < JSTEPS; js++) {
        __syncthreads();                       // prior step's Vt reads done
        *(short4v*)(&Vt[sr][sc * 4]) = vreg;
        int jn = (js + 1 < JSTEPS) ? js + 1 : js;   // clamped prefetch index
        vreg = *(const short4v*)(vsrc + jn * 32);
        __syncthreads();                       // Vt visible

        floatx16 st = {};
        st = __builtin_amdgcn_mfma_f32_32x32x16_bf16(ka1, q1, st, 0, 0, 0);
        st = __builtin_amdgcn_mfma_f32_32x32x16_bf16(ka2, q2, st, 0, 0, 0);
        // prefetch next K frags during exp/pack
        const short8* krow = (const short8*)(Kb + (size_t)(chunk * CSIZE + jn * 32 + l31) * RR);
        ka1 = krow[h]; ka2 = krow[2 + h];

        float p[16];
        #pragma unroll
        for (int r = 0; r < 16; r++) { p[r] = exp2_fast(st[r]); lacc += p[r]; }
        short8 pa1, pa2;
        #pragma unroll
        for (int r = 0; r < 8; r++) {
            pa1[r] = (short)f2bf(p[r]);
            pa2[r] = (short)f2bf(p[r + 8]);
        }
        // V B-frags from LDS, k-order matches C-frag reg order
        const unsigned short* vrow = &Vt[l31][0];
        short4v v0 = *(const short4v*)(vrow + 4 * h);
        short4v v1 = *(const short4v*)(vrow + 8 + 4 * h);
        short4v v2 = *(const short4v*)(vrow + 16 + 4 * h);
        short4v v3 = *(const short4v*)(vrow + 24 + 4 * h);
        short8 vb1, vb2;
        #pragma unroll
        for (int q = 0; q < 4; q++) {
            vb1[q] = v0[q]; vb1[q + 4] = v1[q];
            vb2[q] = v2[q]; vb2[q + 4] = v3[q];
        }
        acc = __builtin_amdgcn_mfma_f32_32x32x16_bf16(pa1, vb1, acc, 0, 0, 0);
        acc = __builtin_amdgcn_mfma_f32_32x32x16_bf16(pa2, vb2, acc, 0, 0, 0);
    }
    size_t slot = ((size_t)(b * 128 + itile) * NCHUNK + chunk) * 64 + lane;
    float* op = OP + slot * 16;
    #pragma unroll
    for (int r = 0; r < 16; r++) op[r] = acc[r];
    LP[slot] = lacc;
}

// ---------------- K3: merge chunk partials -> Fpmap[b][c][i] fp32 -----------
__global__ void k_merge(const float* __restrict__ OP, const float* __restrict__ LP,
                        float* __restrict__ FM) {
    int itile = blockIdx.x, b = blockIdx.y;
    int lane = threadIdx.x, l31 = lane & 31, h = lane >> 5;
    __shared__ float linv[32];
    size_t base = (size_t)(b * 128 + itile) * NCHUNK;
    float ls = 0.f;
    #pragma unroll
    for (int ch = 0; ch < NCHUNK; ch++) ls += LP[(base + ch) * 64 + lane];
    ls += __shfl_xor(ls, 32, 64);                  // combine the two j-halves
    if (lane < 32) linv[lane] = 1.f / ls;          // index = i_local = l31
    __syncthreads();
    float o[16];
    #pragma unroll
    for (int r = 0; r < 16; r++) o[r] = 0.f;
    for (int ch = 0; ch < NCHUNK; ch++) {
        const float* op = OP + ((base + ch) * 64 + lane) * 16;
        #pragma unroll
        for (int r = 0; r < 16; r++) o[r] += op[r];
    }
    int ibase = itile * 32;
    float* fm = FM + (size_t)b * RR * NN;
    #pragma unroll
    for (int r = 0; r < 16; r++) {
        int il = (r & 3) + 8 * (r >> 2) + 4 * h;   // C/D row mapping (m74/m101)
        fm[(size_t)l31 * NN + ibase + il] = o[r] * linv[il];
    }
}

// ---------------- K4: 1x1 conv R->C + bias + residual -----------------------
__global__ void k_convout(const float* __restrict__ x, const float* __restrict__ FM,
                          const float* __restrict__ cw, const float* __restrict__ cb,
                          float* __restrict__ out) {
    int co = blockIdx.y, b = blockIdx.z;
    int n4 = blockIdx.x * 256 + threadIdx.x;       // float4 index, N/4 = 1024
    const float4* fmp = (const float4*)(FM + (size_t)b * RR * NN);
    float ax = 0.f, ay = 0.f, az = 0.f, aw = 0.f;
    #pragma unroll 8
    for (int r = 0; r < RR; r++) {
        float wv = cw[co * RR + r];
        float4 v = fmp[r * (NN / 4) + n4];
        ax += wv * v.x; ay += wv * v.y; az += wv * v.z; aw += wv * v.w;
    }
    size_t o = (size_t)(b * CC + co) * (NN / 4) + n4;
    float4 xv = ((const float4*)x)[o];
    float bias = cb[co];
    float4 res;
    res.x = xv.x + ax + bias; res.y = xv.y + ay + bias;
    res.z = xv.z + az + bias; res.w = xv.w + aw + bias;
    ((float4*)out)[o] = res;
}

extern "C" void kernel_launch(void* const* d_in, const int* in_sizes, int n_in,
                              void* d_out, int out_size, void* d_ws, size_t ws_size,
                              hipStream_t stream) {
    const float* x = (const float*)d_in[0];
    char* ws = (char*)d_ws;
    unsigned short* Qt = (unsigned short*)(ws);               // 1 MB  (b,n,r) bf16 *log2e
    unsigned short* Kt = (unsigned short*)(ws + 1048576);     // 1 MB  (b,n,r) bf16
    unsigned short* V  = (unsigned short*)(ws + 2097152);     // 1 MB  (b,r,n) bf16
    float*          OP = (float*)(ws + 3145728);              // 16 MB attention O partials
    float*          LP = (float*)(ws + 19922944);             // 1 MB  softmax-denom partials
    float*          FM = (float*)(ws + 20971520);             // 2 MB  Fpmap (b,r,n) fp32

    hipLaunchKernelGGL(k_qkv, dim3(64, BB), dim3(512), 0, stream, x,
                       (const float*)d_in[1], (const float*)d_in[2],
                       (const float*)d_in[3], (const float*)d_in[4],
                       (const float*)d_in[5], (const float*)d_in[6],
                       (const float*)d_in[7], (const float*)d_in[8],
                       (const float*)d_in[9], (const float*)d_in[10],
                       (const float*)d_in[11], (const float*)d_in[12],
                       V, Qt, Kt);
    hipLaunchKernelGGL(k_attn, dim3(32, NCHUNK, BB), dim3(256), 0, stream, Qt, Kt, V, OP, LP);
    hipLaunchKernelGGL(k_merge, dim3(128, BB), dim3(64), 0, stream, OP, LP, FM);
    hipLaunchKernelGGL(k_convout, dim3(4, CC, BB), dim3(256), 0, stream,
                       x, FM, (const float*)d_in[13], (const float*)d_in[14], (float*)d_out);
}